// Round 1
// baseline (4764.061 us; speedup 1.0000x reference)
//
#include <hip/hip_runtime.h>
#include <math.h>

#define NTHR 64
#define ROWS 4
#define N_ROWS 80000
#define PU 488   // union region: x row (480) / Sk(0..255)+mb(260..387)
#define PC 164   // cat: s_k(128) | n_k(32) | p0 @160
#define PV 196   // v_k: j*3+m (192)

__device__ __forceinline__ float wsum64(float v) {
  #pragma unroll
  for (int m = 1; m < 64; m <<= 1) v += __shfl_xor(v, m, 64);
  return v;
}

// acc[m][r] += sum_i lds[r][off + i*3+m] * W[i*64 + j0]   (i = 0..63)
__device__ __forceinline__ void contract64(const float* __restrict__ W, int j0,
                                           const float* lds, int pitch, int off,
                                           float acc[3][ROWS]) {
  #pragma unroll 2
  for (int ic = 0; ic < 16; ++ic) {
    float wt[4];
    #pragma unroll
    for (int ii = 0; ii < 4; ++ii) wt[ii] = W[(ic * 4 + ii) * 64 + j0];
    #pragma unroll
    for (int r = 0; r < ROWS; ++r) {
      const float* p = lds + r * pitch + off + ic * 12;
      float4 q0 = *(const float4*)p;
      float4 q1 = *(const float4*)(p + 4);
      float4 q2 = *(const float4*)(p + 8);
      float xv[12] = {q0.x,q0.y,q0.z,q0.w, q1.x,q1.y,q1.z,q1.w, q2.x,q2.y,q2.z,q2.w};
      #pragma unroll
      for (int ii = 0; ii < 4; ++ii)
        #pragma unroll
        for (int m = 0; m < 3; ++m)
          acc[m][r] = fmaf(xv[ii * 3 + m], wt[ii], acc[m][r]);
    }
  }
}

__global__ __launch_bounds__(NTHR, 4)
void efb_kernel(const float* __restrict__ x0, const float* __restrict__ x1,
                const float* __restrict__ x2, const float* __restrict__ x3,
                const float* __restrict__ Wl0, const float* __restrict__ Wl1,
                const float* __restrict__ Wl2, const float* __restrict__ Wtp0,
                const float* __restrict__ Wtp1, const float* __restrict__ Wsm,
                const float* __restrict__ bsv, const float* __restrict__ Wv1o,
                const float* __restrict__ Wv1e, const float* __restrict__ gma,
                const float* __restrict__ bta, const float* __restrict__ Wm1,
                const float* __restrict__ bm1, const float* __restrict__ Wm2,
                const float* __restrict__ bm2, float* __restrict__ out)
{
  __shared__ float U[ROWS * PU];
  __shared__ float cat[ROWS * PC];
  __shared__ float vbuf[ROWS * PV];

  const int lane = threadIdx.x;      // 64 lanes = feature columns
  const int j0 = lane;
  const int j2 = lane & 31, half = lane >> 5;   // stage D mapping
  const int row0 = blockIdx.x * ROWS;

  const float INV0 = 0.08838834764831845f;   // 1/sqrt(128)
  const float INV1 = 0.125f;                 // 1/sqrt(64)
  const float INV2 = 0.17677669529663687f;   // 1/sqrt(32)
  const float P0S  = 0.009021097956087907f;  // 1/(sqrt(3)*64)
  const float P1S  = 0.011048543456039806f;  // 1/(sqrt(2)*64)

  // persistent per-lane state
  float Nm0[4][ROWS];     // softmax numerator for S (cols j0+64t)
  float vnum[3][ROWS];    // numerator for v1o part (col j0, 3 comps)
  float ne[3][ROWS];      // numerator for v1e part (col j0)
  float vpr[3][ROWS];     // v_{k-1}[r][j0][m]
  float mx[ROWS], Zz[ROWS];
  #pragma unroll
  for (int r = 0; r < ROWS; ++r) {
    mx[r] = -1e30f; Zz[r] = 0.f;
    #pragma unroll
    for (int t = 0; t < 4; ++t) Nm0[t][r] = 0.f;
    #pragma unroll
    for (int m = 0; m < 3; ++m) { vnum[m][r] = 0.f; ne[m][r] = 0.f; vpr[m][r] = 0.f; }
  }

  for (int k = 0; k < 4; ++k) {
    const float* gx = (k == 0) ? x0 : (k == 1) ? x1 : (k == 2) ? x2 : x3;
    gx += (size_t)row0 * 480;

    __syncthreads();   // prior k's broadcast reads of U done before rewrite
    // ---- A: stage x tile ----
    #pragma unroll
    for (int r = 0; r < ROWS; ++r)
      for (int c = lane; c < 120; c += 64) {
        float4 q = ((const float4*)gx)[r * 120 + c];
        *(float4*)&U[r * PU + c * 4] = q;
      }
    __syncthreads();

    // ---- B: s_k = x_s @ Wl0[k] * INV0 -> cat[0:128] ----
    {
      const float* W = Wl0 + k * 16384;
      float a0[ROWS] = {}, a1[ROWS] = {};
      #pragma unroll 2
      for (int ic = 0; ic < 32; ++ic) {
        float wt0[4], wt1[4];
        #pragma unroll
        for (int ii = 0; ii < 4; ++ii) {
          wt0[ii] = W[(ic * 4 + ii) * 128 + j0];
          wt1[ii] = W[(ic * 4 + ii) * 128 + 64 + j0];
        }
        #pragma unroll
        for (int r = 0; r < ROWS; ++r) {
          float4 q = *(const float4*)&U[r * PU + ic * 4];
          float xv[4] = {q.x, q.y, q.z, q.w};
          #pragma unroll
          for (int ii = 0; ii < 4; ++ii) {
            a0[r] = fmaf(xv[ii], wt0[ii], a0[r]);
            a1[r] = fmaf(xv[ii], wt1[ii], a1[r]);
          }
        }
      }
      #pragma unroll
      for (int r = 0; r < ROWS; ++r) {
        cat[r * PC + j0]      = a0[r] * INV0;
        cat[r * PC + 64 + j0] = a1[r] * INV0;
      }
    }

    // ---- C: v_k[r][j0][m] ----
    float vtmp[3][ROWS];
    {
      float ac[3][ROWS] = {};
      contract64(Wl1 + k * 4096, j0, U, PU, 128, ac);
      #pragma unroll
      for (int r = 0; r < ROWS; ++r)
        #pragma unroll
        for (int m = 0; m < 3; ++m) {
          vtmp[m][r] = ac[m][r] * INV1;
          vbuf[r * PV + j0 * 3 + m] = vtmp[m][r];
        }
    }

    // ---- D: n_k -> cat[128:160] ----
    {
      constexpr int RH = ROWS / 2;   // rows handled per 32-lane half
      const float* W = Wl2 + k * 1024;
      float t5[5][RH] = {};
      #pragma unroll 2
      for (int ic = 0; ic < 8; ++ic) {
        float wt[4];
        #pragma unroll
        for (int ii = 0; ii < 4; ++ii) wt[ii] = W[(ic * 4 + ii) * 32 + j2];
        #pragma unroll
        for (int rr = 0; rr < RH; ++rr) {
          const float* p = &U[(half * RH + rr) * PU + 320 + ic * 20];
          float xt[20];
          #pragma unroll
          for (int q4 = 0; q4 < 5; ++q4) {
            float4 q = *(const float4*)(p + q4 * 4);
            xt[q4*4] = q.x; xt[q4*4+1] = q.y; xt[q4*4+2] = q.z; xt[q4*4+3] = q.w;
          }
          #pragma unroll
          for (int ii = 0; ii < 4; ++ii)
            #pragma unroll
            for (int m = 0; m < 5; ++m)
              t5[m][rr] = fmaf(xt[ii * 5 + m], wt[ii], t5[m][rr]);
        }
      }
      #pragma unroll
      for (int rr = 0; rr < RH; ++rr) {
        float s = 0.f;
        #pragma unroll
        for (int m = 0; m < 5; ++m) { float tt = t5[m][rr] * INV2; s = fmaf(tt, tt, s); }
        cat[(half * RH + rr) * PC + 128 + j2] = sqrtf(s);
      }
    }
    __syncthreads();

    // ---- E: p0, p1 ----
    float p1[3][ROWS], np1[ROWS];
    if (k > 0) {
      {
        float u0[3][ROWS] = {};
        contract64(Wtp0, j0, vbuf, PV, 0, u0);
        #pragma unroll
        for (int r = 0; r < ROWS; ++r) {
          float s = 0.f;
          #pragma unroll
          for (int m = 0; m < 3; ++m) s = fmaf(u0[m][r], vpr[m][r], s);
          s = wsum64(s) * P0S;
          if (lane == r) cat[r * PC + 160] = s;
        }
      }
      {
        float u1[3][ROWS] = {};
        contract64(Wtp1, j0, vbuf, PV, 0, u1);
        #pragma unroll
        for (int r = 0; r < ROWS; ++r) {
          float c0 = u1[1][r] * vpr[2][r] - u1[2][r] * vpr[1][r];
          float c1 = u1[2][r] * vpr[0][r] - u1[0][r] * vpr[2][r];
          float c2 = u1[0][r] * vpr[1][r] - u1[1][r] * vpr[0][r];
          p1[0][r] = wsum64(c0) * P1S;
          p1[1][r] = wsum64(c1) * P1S;
          p1[2][r] = wsum64(c2) * P1S;
          np1[r] = sqrtf(p1[0][r]*p1[0][r] + p1[1][r]*p1[1][r] + p1[2][r]*p1[2][r]);
        }
      }
    } else {
      #pragma unroll
      for (int r = 0; r < ROWS; ++r) {
        #pragma unroll
        for (int m = 0; m < 3; ++m) p1[m][r] = 0.f;
        np1[r] = 0.f;
        if (lane == r) cat[r * PC + 160] = 0.f;
      }
    }
    // v_prev <- v_k
    #pragma unroll
    for (int r = 0; r < ROWS; ++r)
      #pragma unroll
      for (int m = 0; m < 3; ++m) vpr[m][r] = vtmp[m][r];
    __syncthreads();

    // ---- F: s_tilde -> U[0:256] (Sk) ----
    {
      const float* W = Wsm + k * 41216;
      float ac4[4][ROWS] = {};
      #pragma unroll 2
      for (int ic = 0; ic < 40; ++ic) {
        float w4[4][4];
        #pragma unroll
        for (int ii = 0; ii < 4; ++ii)
          #pragma unroll
          for (int t = 0; t < 4; ++t) w4[ii][t] = W[(ic * 4 + ii) * 256 + t * 64 + j0];
        #pragma unroll
        for (int r = 0; r < ROWS; ++r) {
          float4 q = *(const float4*)&cat[r * PC + ic * 4];
          float cv[4] = {q.x, q.y, q.z, q.w};
          #pragma unroll
          for (int ii = 0; ii < 4; ++ii)
            #pragma unroll
            for (int t = 0; t < 4; ++t)
              ac4[t][r] = fmaf(cv[ii], w4[ii][t], ac4[t][r]);
        }
      }
      { // a = 160 (p0 term)
        float w4[4];
        #pragma unroll
        for (int t = 0; t < 4; ++t) w4[t] = W[160 * 256 + t * 64 + j0];
        #pragma unroll
        for (int r = 0; r < ROWS; ++r) {
          float c = cat[r * PC + 160];
          #pragma unroll
          for (int t = 0; t < 4; ++t) ac4[t][r] = fmaf(c, w4[t], ac4[t][r]);
        }
      }
      float bt[4];
      #pragma unroll
      for (int t = 0; t < 4; ++t) bt[t] = bsv[k * 256 + t * 64 + j0];
      #pragma unroll
      for (int r = 0; r < ROWS; ++r)
        #pragma unroll
        for (int t = 0; t < 4; ++t)
          U[r * PU + t * 64 + j0] = ac4[t][r] + bt[t];
    }

    // ---- G: v1o + mb ----
    float vo[3][ROWS], mbS[ROWS], mbE[ROWS];
    float wv = Wv1e[k * 64 + j0];
    {
      float ac[3][ROWS] = {};
      contract64(Wv1o + k * 4096, j0, vbuf, PV, 0, ac);
      float awv = fabsf(wv);
      #pragma unroll
      for (int r = 0; r < ROWS; ++r) {
        float s = 0.f;
        #pragma unroll
        for (int m = 0; m < 3; ++m) { vo[m][r] = ac[m][r] * INV1; s = fmaf(vo[m][r], vo[m][r], s); }
        mbS[r] = sqrtf(s);
        mbE[r] = np1[r] * awv;
        U[r * PU + 260 + j0] = mbS[r];
        U[r * PU + 260 + 64 + j0] = mbE[r];
      }
    }
    __syncthreads();

    // ---- H: layernorm stats ----
    float mu8[ROWS], rs8[ROWS];
    #pragma unroll
    for (int r = 0; r < ROWS; ++r) {
      float s = 0.f, sq = 0.f;
      #pragma unroll
      for (int t = 0; t < 4; ++t) {
        float v = U[r * PU + t * 64 + j0];
        s += v; sq = fmaf(v, v, sq);
      }
      s += mbS[r] + mbE[r];
      sq = fmaf(mbS[r], mbS[r], sq); sq = fmaf(mbE[r], mbE[r], sq);
      s = wsum64(s); sq = wsum64(sq);
      mu8[r] = s * (1.f / 384.f);
      float var = sq * (1.f / 384.f) - mu8[r] * mu8[r];
      rs8[r] = rsqrtf(var + 1e-5f);
    }

    // ---- I: e_k ----
    float E8[ROWS];
    {
      float A8[ROWS] = {};
      float B0 = 0.f, C0 = 0.f;
      #pragma unroll 2
      for (int ic = 0; ic < 64; ++ic) {
        float wv4[4], gv4[4], bv4[4];
        #pragma unroll
        for (int ii = 0; ii < 4; ++ii) {
          int f = ic * 4 + ii;
          wv4[ii] = Wm1[f * 64 + j0]; gv4[ii] = gma[f]; bv4[ii] = bta[f];
        }
        float gw[4];
        #pragma unroll
        for (int ii = 0; ii < 4; ++ii) {
          gw[ii] = gv4[ii] * wv4[ii];
          B0 += gw[ii];
          C0 = fmaf(bv4[ii], wv4[ii], C0);
        }
        #pragma unroll
        for (int r = 0; r < ROWS; ++r) {
          float4 q = *(const float4*)&U[r * PU + ic * 4];
          float xv[4] = {q.x, q.y, q.z, q.w};
          #pragma unroll
          for (int ii = 0; ii < 4; ++ii) A8[r] = fmaf(xv[ii], gw[ii], A8[r]);
        }
      }
      #pragma unroll 2
      for (int ic = 0; ic < 32; ++ic) {
        float wv4[4], gv4[4], bv4[4];
        #pragma unroll
        for (int ii = 0; ii < 4; ++ii) {
          int f = 256 + ic * 4 + ii;
          wv4[ii] = Wm1[f * 64 + j0]; gv4[ii] = gma[f]; bv4[ii] = bta[f];
        }
        float gw[4];
        #pragma unroll
        for (int ii = 0; ii < 4; ++ii) {
          gw[ii] = gv4[ii] * wv4[ii];
          B0 += gw[ii];
          C0 = fmaf(bv4[ii], wv4[ii], C0);
        }
        #pragma unroll
        for (int r = 0; r < ROWS; ++r) {
          float4 q = *(const float4*)&U[r * PU + 260 + ic * 4];
          float xv[4] = {q.x, q.y, q.z, q.w};
          #pragma unroll
          for (int ii = 0; ii < 4; ++ii) A8[r] = fmaf(xv[ii], gw[ii], A8[r]);
        }
      }
      float b1 = bm1[j0], w2 = Wm2[j0], b2v = bm2[0];
      #pragma unroll
      for (int r = 0; r < ROWS; ++r) {
        float y = rs8[r] * (A8[r] - mu8[r] * B0) + C0 + b1;
        float sl = y / (1.f + expf(-y));
        E8[r] = wsum64(sl * w2) + b2v;
      }
    }

    // ---- J: online softmax update ----
    #pragma unroll
    for (int r = 0; r < ROWS; ++r) {
      float mxn = fmaxf(mx[r], E8[r]);
      float rf = expf(mx[r] - mxn);
      float w = expf(E8[r] - mxn);
      Zz[r] = Zz[r] * rf + w;
      mx[r] = mxn;
      #pragma unroll
      for (int t = 0; t < 4; ++t) {
        float skv = U[r * PU + t * 64 + j0];
        Nm0[t][r] = fmaf(Nm0[t][r], rf, w * skv);
      }
      #pragma unroll
      for (int m = 0; m < 3; ++m) {
        vnum[m][r] = fmaf(vnum[m][r], rf, w * vo[m][r]);
        ne[m][r]   = fmaf(ne[m][r],   rf, w * (p1[m][r] * wv));
      }
    }
  }

  // ---- epilogue ----
  __syncthreads();
  float iz[ROWS];
  #pragma unroll
  for (int r = 0; r < ROWS; ++r) iz[r] = 1.f / Zz[r];
  #pragma unroll
  for (int r = 0; r < ROWS; ++r)
    #pragma unroll
    for (int t = 0; t < 4; ++t)
      out[(size_t)(row0 + r) * 256 + t * 64 + j0] = Nm0[t][r] * iz[r];
  #pragma unroll
  for (int r = 0; r < ROWS; ++r)
    #pragma unroll
    for (int m = 0; m < 3; ++m) {
      U[r * PU + j0 * 3 + m]       = vnum[m][r] * iz[r];
      U[r * PU + 192 + j0 * 3 + m] = ne[m][r] * iz[r];
    }
  __syncthreads();
  const size_t o1 = (size_t)N_ROWS * 256;
  #pragma unroll
  for (int r = 0; r < ROWS; ++r)
    for (int c = lane; c < 96; c += 64) {
      float4 q = *(const float4*)&U[r * PU + c * 4];
      *(float4*)&out[o1 + (size_t)(row0 + r) * 384 + c * 4] = q;
    }
}

extern "C" void kernel_launch(void* const* d_in, const int* in_sizes, int n_in,
                              void* d_out, int out_size, void* d_ws, size_t ws_size,
                              hipStream_t stream) {
  const float* x0   = (const float*)d_in[0];
  const float* x1   = (const float*)d_in[1];
  const float* x2   = (const float*)d_in[2];
  const float* x3   = (const float*)d_in[3];
  const float* Wl0  = (const float*)d_in[4];
  const float* Wl1  = (const float*)d_in[5];
  const float* Wl2  = (const float*)d_in[6];
  const float* Wtp0 = (const float*)d_in[7];
  const float* Wtp1 = (const float*)d_in[8];
  const float* Wsm  = (const float*)d_in[9];
  const float* bsv  = (const float*)d_in[10];
  const float* Wv1o = (const float*)d_in[11];
  const float* Wv1e = (const float*)d_in[12];
  const float* gma  = (const float*)d_in[13];
  const float* bta  = (const float*)d_in[14];
  const float* Wm1  = (const float*)d_in[15];
  const float* bm1  = (const float*)d_in[16];
  const float* Wm2  = (const float*)d_in[17];
  const float* bm2  = (const float*)d_in[18];
  float* out = (float*)d_out;

  dim3 grid(N_ROWS / ROWS), block(NTHR);
  efb_kernel<<<grid, block, 0, stream>>>(
      x0, x1, x2, x3, Wl0, Wl1, Wl2, Wtp0, Wtp1, Wsm, bsv,
      Wv1o, Wv1e, gma, bta, Wm1, bm1, Wm2, bm2, out);
}

// Round 2
// 4078.326 us; speedup vs baseline: 1.1681x; 1.1681x over previous
//
#include <hip/hip_runtime.h>
#include <math.h>

#define NTHR 256            // 4 waves per block
#define WPB 4               // waves per block
#define ROWS 4              // rows per wave
#define RPB (WPB * ROWS)    // 16 rows per block
#define N_ROWS 80000
#define PU 488   // union region: x row (480) / Sk(0..255)+mb(260..387)
#define PC 164   // cat: s_k(128) | n_k(32) | p0 @160
#define PV 196   // v_k: j*3+m (192)

__device__ __forceinline__ float wsum64(float v) {
  #pragma unroll
  for (int m = 1; m < 64; m <<= 1) v += __shfl_xor(v, m, 64);
  return v;
}

// acc[m][r] += sum_i lds[r][off + i*3+m] * W[i*64 + j0]   (i = 0..63)
__device__ __forceinline__ void contract64(const float* __restrict__ W, int j0,
                                           const float* lds, int pitch, int off,
                                           float acc[3][ROWS]) {
  #pragma unroll 2
  for (int ic = 0; ic < 16; ++ic) {
    float wt[4];
    #pragma unroll
    for (int ii = 0; ii < 4; ++ii) wt[ii] = W[(ic * 4 + ii) * 64 + j0];
    #pragma unroll
    for (int r = 0; r < ROWS; ++r) {
      const float* p = lds + r * pitch + off + ic * 12;
      float4 q0 = *(const float4*)p;
      float4 q1 = *(const float4*)(p + 4);
      float4 q2 = *(const float4*)(p + 8);
      float xv[12] = {q0.x,q0.y,q0.z,q0.w, q1.x,q1.y,q1.z,q1.w, q2.x,q2.y,q2.z,q2.w};
      #pragma unroll
      for (int ii = 0; ii < 4; ++ii)
        #pragma unroll
        for (int m = 0; m < 3; ++m)
          acc[m][r] = fmaf(xv[ii * 3 + m], wt[ii], acc[m][r]);
    }
  }
}

__global__ __launch_bounds__(NTHR, 3)
void efb_kernel(const float* __restrict__ x0, const float* __restrict__ x1,
                const float* __restrict__ x2, const float* __restrict__ x3,
                const float* __restrict__ Wl0, const float* __restrict__ Wl1,
                const float* __restrict__ Wl2, const float* __restrict__ Wtp0,
                const float* __restrict__ Wtp1, const float* __restrict__ Wsm,
                const float* __restrict__ bsv, const float* __restrict__ Wv1o,
                const float* __restrict__ Wv1e, const float* __restrict__ gma,
                const float* __restrict__ bta, const float* __restrict__ Wm1,
                const float* __restrict__ bm1, const float* __restrict__ Wm2,
                const float* __restrict__ bm2, float* __restrict__ out)
{
  __shared__ float U[WPB * ROWS * PU];
  __shared__ float cat[WPB * ROWS * PC];
  __shared__ float vbuf[WPB * ROWS * PV];

  const int tid = threadIdx.x;
  const int wid = tid >> 6;          // wave id 0..3, owns its own 4-row group
  const int lane = tid & 63;         // 64 lanes = feature columns
  const int j0 = lane;
  const int j2 = lane & 31, half = lane >> 5;   // stage D mapping

  float* Uw  = U    + wid * ROWS * PU;
  float* catw = cat + wid * ROWS * PC;
  float* vbw = vbuf + wid * ROWS * PV;
  const int row0 = blockIdx.x * RPB + wid * ROWS;

  const float INV0 = 0.08838834764831845f;   // 1/sqrt(128)
  const float INV1 = 0.125f;                 // 1/sqrt(64)
  const float INV2 = 0.17677669529663687f;   // 1/sqrt(32)
  const float P0S  = 0.009021097956087907f;  // 1/(sqrt(3)*64)
  const float P1S  = 0.011048543456039806f;  // 1/(sqrt(2)*64)

  // persistent per-lane state
  float Nm0[4][ROWS];     // softmax numerator for S (cols j0+64t)
  float vnum[3][ROWS];    // numerator for v1o part (col j0, 3 comps)
  float ne[3][ROWS];      // numerator for v1e part (col j0)
  float vpr[3][ROWS];     // v_{k-1}[r][j0][m]
  float mx[ROWS], Zz[ROWS];
  #pragma unroll
  for (int r = 0; r < ROWS; ++r) {
    mx[r] = -1e30f; Zz[r] = 0.f;
    #pragma unroll
    for (int t = 0; t < 4; ++t) Nm0[t][r] = 0.f;
    #pragma unroll
    for (int m = 0; m < 3; ++m) { vnum[m][r] = 0.f; ne[m][r] = 0.f; vpr[m][r] = 0.f; }
  }

  for (int k = 0; k < 4; ++k) {
    const float* gx = (k == 0) ? x0 : (k == 1) ? x1 : (k == 2) ? x2 : x3;
    gx += (size_t)row0 * 480;

    __syncthreads();   // prior k's broadcast reads of U done before rewrite
    // ---- A: stage x tile ----
    #pragma unroll
    for (int r = 0; r < ROWS; ++r)
      for (int c = lane; c < 120; c += 64) {
        float4 q = ((const float4*)gx)[r * 120 + c];
        *(float4*)&Uw[r * PU + c * 4] = q;
      }
    __syncthreads();

    // ---- B: s_k = x_s @ Wl0[k] * INV0 -> cat[0:128] ----
    {
      const float* W = Wl0 + k * 16384;
      float a0[ROWS] = {}, a1[ROWS] = {};
      #pragma unroll 2
      for (int ic = 0; ic < 32; ++ic) {
        float wt0[4], wt1[4];
        #pragma unroll
        for (int ii = 0; ii < 4; ++ii) {
          wt0[ii] = W[(ic * 4 + ii) * 128 + j0];
          wt1[ii] = W[(ic * 4 + ii) * 128 + 64 + j0];
        }
        #pragma unroll
        for (int r = 0; r < ROWS; ++r) {
          float4 q = *(const float4*)&Uw[r * PU + ic * 4];
          float xv[4] = {q.x, q.y, q.z, q.w};
          #pragma unroll
          for (int ii = 0; ii < 4; ++ii) {
            a0[r] = fmaf(xv[ii], wt0[ii], a0[r]);
            a1[r] = fmaf(xv[ii], wt1[ii], a1[r]);
          }
        }
      }
      #pragma unroll
      for (int r = 0; r < ROWS; ++r) {
        catw[r * PC + j0]      = a0[r] * INV0;
        catw[r * PC + 64 + j0] = a1[r] * INV0;
      }
    }

    // ---- C: v_k[r][j0][m] ----
    float vtmp[3][ROWS];
    {
      float ac[3][ROWS] = {};
      contract64(Wl1 + k * 4096, j0, Uw, PU, 128, ac);
      #pragma unroll
      for (int r = 0; r < ROWS; ++r)
        #pragma unroll
        for (int m = 0; m < 3; ++m) {
          vtmp[m][r] = ac[m][r] * INV1;
          vbw[r * PV + j0 * 3 + m] = vtmp[m][r];
        }
    }

    // ---- D: n_k -> cat[128:160] ----
    {
      constexpr int RH = ROWS / 2;   // rows handled per 32-lane half
      const float* W = Wl2 + k * 1024;
      float t5[5][RH] = {};
      #pragma unroll 2
      for (int ic = 0; ic < 8; ++ic) {
        float wt[4];
        #pragma unroll
        for (int ii = 0; ii < 4; ++ii) wt[ii] = W[(ic * 4 + ii) * 32 + j2];
        #pragma unroll
        for (int rr = 0; rr < RH; ++rr) {
          const float* p = &Uw[(half * RH + rr) * PU + 320 + ic * 20];
          float xt[20];
          #pragma unroll
          for (int q4 = 0; q4 < 5; ++q4) {
            float4 q = *(const float4*)(p + q4 * 4);
            xt[q4*4] = q.x; xt[q4*4+1] = q.y; xt[q4*4+2] = q.z; xt[q4*4+3] = q.w;
          }
          #pragma unroll
          for (int ii = 0; ii < 4; ++ii)
            #pragma unroll
            for (int m = 0; m < 5; ++m)
              t5[m][rr] = fmaf(xt[ii * 5 + m], wt[ii], t5[m][rr]);
        }
      }
      #pragma unroll
      for (int rr = 0; rr < RH; ++rr) {
        float s = 0.f;
        #pragma unroll
        for (int m = 0; m < 5; ++m) { float tt = t5[m][rr] * INV2; s = fmaf(tt, tt, s); }
        catw[(half * RH + rr) * PC + 128 + j2] = sqrtf(s);
      }
    }
    __syncthreads();

    // ---- E: p0, p1 ----
    float p1[3][ROWS], np1[ROWS];
    if (k > 0) {
      {
        float u0[3][ROWS] = {};
        contract64(Wtp0, j0, vbw, PV, 0, u0);
        #pragma unroll
        for (int r = 0; r < ROWS; ++r) {
          float s = 0.f;
          #pragma unroll
          for (int m = 0; m < 3; ++m) s = fmaf(u0[m][r], vpr[m][r], s);
          s = wsum64(s) * P0S;
          if (lane == r) catw[r * PC + 160] = s;
        }
      }
      {
        float u1[3][ROWS] = {};
        contract64(Wtp1, j0, vbw, PV, 0, u1);
        #pragma unroll
        for (int r = 0; r < ROWS; ++r) {
          float c0 = u1[1][r] * vpr[2][r] - u1[2][r] * vpr[1][r];
          float c1 = u1[2][r] * vpr[0][r] - u1[0][r] * vpr[2][r];
          float c2 = u1[0][r] * vpr[1][r] - u1[1][r] * vpr[0][r];
          p1[0][r] = wsum64(c0) * P1S;
          p1[1][r] = wsum64(c1) * P1S;
          p1[2][r] = wsum64(c2) * P1S;
          np1[r] = sqrtf(p1[0][r]*p1[0][r] + p1[1][r]*p1[1][r] + p1[2][r]*p1[2][r]);
        }
      }
    } else {
      #pragma unroll
      for (int r = 0; r < ROWS; ++r) {
        #pragma unroll
        for (int m = 0; m < 3; ++m) p1[m][r] = 0.f;
        np1[r] = 0.f;
        if (lane == r) catw[r * PC + 160] = 0.f;
      }
    }
    // v_prev <- v_k
    #pragma unroll
    for (int r = 0; r < ROWS; ++r)
      #pragma unroll
      for (int m = 0; m < 3; ++m) vpr[m][r] = vtmp[m][r];
    __syncthreads();

    // ---- F: s_tilde -> U[0:256] (Sk) + register copy ----
    float sk[4][ROWS];
    {
      const float* W = Wsm + k * 41216;
      float ac4[4][ROWS] = {};
      #pragma unroll 2
      for (int ic = 0; ic < 40; ++ic) {
        float w4[4][4];
        #pragma unroll
        for (int ii = 0; ii < 4; ++ii)
          #pragma unroll
          for (int t = 0; t < 4; ++t) w4[ii][t] = W[(ic * 4 + ii) * 256 + t * 64 + j0];
        #pragma unroll
        for (int r = 0; r < ROWS; ++r) {
          float4 q = *(const float4*)&catw[r * PC + ic * 4];
          float cv[4] = {q.x, q.y, q.z, q.w};
          #pragma unroll
          for (int ii = 0; ii < 4; ++ii)
            #pragma unroll
            for (int t = 0; t < 4; ++t)
              ac4[t][r] = fmaf(cv[ii], w4[ii][t], ac4[t][r]);
        }
      }
      { // a = 160 (p0 term)
        float w4[4];
        #pragma unroll
        for (int t = 0; t < 4; ++t) w4[t] = W[160 * 256 + t * 64 + j0];
        #pragma unroll
        for (int r = 0; r < ROWS; ++r) {
          float c = catw[r * PC + 160];
          #pragma unroll
          for (int t = 0; t < 4; ++t) ac4[t][r] = fmaf(c, w4[t], ac4[t][r]);
        }
      }
      float bt[4];
      #pragma unroll
      for (int t = 0; t < 4; ++t) bt[t] = bsv[k * 256 + t * 64 + j0];
      #pragma unroll
      for (int r = 0; r < ROWS; ++r)
        #pragma unroll
        for (int t = 0; t < 4; ++t) {
          sk[t][r] = ac4[t][r] + bt[t];
          Uw[r * PU + t * 64 + j0] = sk[t][r];
        }
    }

    // ---- G: v1o + mb ----
    float vo[3][ROWS], mbS[ROWS], mbE[ROWS];
    float wv = Wv1e[k * 64 + j0];
    {
      float ac[3][ROWS] = {};
      contract64(Wv1o + k * 4096, j0, vbw, PV, 0, ac);
      float awv = fabsf(wv);
      #pragma unroll
      for (int r = 0; r < ROWS; ++r) {
        float s = 0.f;
        #pragma unroll
        for (int m = 0; m < 3; ++m) { vo[m][r] = ac[m][r] * INV1; s = fmaf(vo[m][r], vo[m][r], s); }
        mbS[r] = sqrtf(s);
        mbE[r] = np1[r] * awv;
        Uw[r * PU + 260 + j0] = mbS[r];
        Uw[r * PU + 260 + 64 + j0] = mbE[r];
      }
    }
    __syncthreads();

    // ---- H: layernorm stats (uses register sk, no LDS re-read) ----
    float mu8[ROWS], rs8[ROWS];
    #pragma unroll
    for (int r = 0; r < ROWS; ++r) {
      float s = 0.f, sq = 0.f;
      #pragma unroll
      for (int t = 0; t < 4; ++t) {
        float v = sk[t][r];
        s += v; sq = fmaf(v, v, sq);
      }
      s += mbS[r] + mbE[r];
      sq = fmaf(mbS[r], mbS[r], sq); sq = fmaf(mbE[r], mbE[r], sq);
      s = wsum64(s); sq = wsum64(sq);
      mu8[r] = s * (1.f / 384.f);
      float var = sq * (1.f / 384.f) - mu8[r] * mu8[r];
      rs8[r] = rsqrtf(var + 1e-5f);
    }

    // ---- I: e_k ----
    float E8[ROWS];
    {
      float A8[ROWS] = {};
      float B0 = 0.f, C0 = 0.f;
      #pragma unroll 2
      for (int ic = 0; ic < 64; ++ic) {
        float wv4[4], gv4[4], bv4[4];
        #pragma unroll
        for (int ii = 0; ii < 4; ++ii) {
          int f = ic * 4 + ii;
          wv4[ii] = Wm1[f * 64 + j0]; gv4[ii] = gma[f]; bv4[ii] = bta[f];
        }
        float gw[4];
        #pragma unroll
        for (int ii = 0; ii < 4; ++ii) {
          gw[ii] = gv4[ii] * wv4[ii];
          B0 += gw[ii];
          C0 = fmaf(bv4[ii], wv4[ii], C0);
        }
        #pragma unroll
        for (int r = 0; r < ROWS; ++r) {
          float4 q = *(const float4*)&Uw[r * PU + ic * 4];
          float xv[4] = {q.x, q.y, q.z, q.w};
          #pragma unroll
          for (int ii = 0; ii < 4; ++ii) A8[r] = fmaf(xv[ii], gw[ii], A8[r]);
        }
      }
      #pragma unroll 2
      for (int ic = 0; ic < 32; ++ic) {
        float wv4[4], gv4[4], bv4[4];
        #pragma unroll
        for (int ii = 0; ii < 4; ++ii) {
          int f = 256 + ic * 4 + ii;
          wv4[ii] = Wm1[f * 64 + j0]; gv4[ii] = gma[f]; bv4[ii] = bta[f];
        }
        float gw[4];
        #pragma unroll
        for (int ii = 0; ii < 4; ++ii) {
          gw[ii] = gv4[ii] * wv4[ii];
          B0 += gw[ii];
          C0 = fmaf(bv4[ii], wv4[ii], C0);
        }
        #pragma unroll
        for (int r = 0; r < ROWS; ++r) {
          float4 q = *(const float4*)&Uw[r * PU + 260 + ic * 4];
          float xv[4] = {q.x, q.y, q.z, q.w};
          #pragma unroll
          for (int ii = 0; ii < 4; ++ii) A8[r] = fmaf(xv[ii], gw[ii], A8[r]);
        }
      }
      float b1 = bm1[j0], w2 = Wm2[j0], b2v = bm2[0];
      #pragma unroll
      for (int r = 0; r < ROWS; ++r) {
        float y = rs8[r] * (A8[r] - mu8[r] * B0) + C0 + b1;
        float sl = y / (1.f + expf(-y));
        E8[r] = wsum64(sl * w2) + b2v;
      }
    }

    // ---- J: online softmax update (uses register sk) ----
    #pragma unroll
    for (int r = 0; r < ROWS; ++r) {
      float mxn = fmaxf(mx[r], E8[r]);
      float rf = expf(mx[r] - mxn);
      float w = expf(E8[r] - mxn);
      Zz[r] = Zz[r] * rf + w;
      mx[r] = mxn;
      #pragma unroll
      for (int t = 0; t < 4; ++t)
        Nm0[t][r] = fmaf(Nm0[t][r], rf, w * sk[t][r]);
      #pragma unroll
      for (int m = 0; m < 3; ++m) {
        vnum[m][r] = fmaf(vnum[m][r], rf, w * vo[m][r]);
        ne[m][r]   = fmaf(ne[m][r],   rf, w * (p1[m][r] * wv));
      }
    }
  }

  // ---- epilogue ----
  __syncthreads();
  float iz[ROWS];
  #pragma unroll
  for (int r = 0; r < ROWS; ++r) iz[r] = 1.f / Zz[r];
  #pragma unroll
  for (int r = 0; r < ROWS; ++r)
    #pragma unroll
    for (int t = 0; t < 4; ++t)
      out[(size_t)(row0 + r) * 256 + t * 64 + j0] = Nm0[t][r] * iz[r];
  #pragma unroll
  for (int r = 0; r < ROWS; ++r)
    #pragma unroll
    for (int m = 0; m < 3; ++m) {
      Uw[r * PU + j0 * 3 + m]       = vnum[m][r] * iz[r];
      Uw[r * PU + 192 + j0 * 3 + m] = ne[m][r] * iz[r];
    }
  __syncthreads();
  const size_t o1 = (size_t)N_ROWS * 256;
  #pragma unroll
  for (int r = 0; r < ROWS; ++r)
    for (int c = lane; c < 96; c += 64) {
      float4 q = *(const float4*)&Uw[r * PU + c * 4];
      *(float4*)&out[o1 + (size_t)(row0 + r) * 384 + c * 4] = q;
    }
}

extern "C" void kernel_launch(void* const* d_in, const int* in_sizes, int n_in,
                              void* d_out, int out_size, void* d_ws, size_t ws_size,
                              hipStream_t stream) {
  const float* x0   = (const float*)d_in[0];
  const float* x1   = (const float*)d_in[1];
  const float* x2   = (const float*)d_in[2];
  const float* x3   = (const float*)d_in[3];
  const float* Wl0  = (const float*)d_in[4];
  const float* Wl1  = (const float*)d_in[5];
  const float* Wl2  = (const float*)d_in[6];
  const float* Wtp0 = (const float*)d_in[7];
  const float* Wtp1 = (const float*)d_in[8];
  const float* Wsm  = (const float*)d_in[9];
  const float* bsv  = (const float*)d_in[10];
  const float* Wv1o = (const float*)d_in[11];
  const float* Wv1e = (const float*)d_in[12];
  const float* gma  = (const float*)d_in[13];
  const float* bta  = (const float*)d_in[14];
  const float* Wm1  = (const float*)d_in[15];
  const float* bm1  = (const float*)d_in[16];
  const float* Wm2  = (const float*)d_in[17];
  const float* bm2  = (const float*)d_in[18];
  float* out = (float*)d_out;

  dim3 grid(N_ROWS / RPB), block(NTHR);
  efb_kernel<<<grid, block, 0, stream>>>(
      x0, x1, x2, x3, Wl0, Wl1, Wl2, Wtp0, Wtp1, Wsm, bsv,
      Wv1o, Wv1e, gma, bta, Wm1, bm1, Wm2, bm2, out);
}